// Round 3
// baseline (1085.819 us; speedup 1.0000x reference)
//
#include <hip/hip_runtime.h>
#include <stdint.h>

typedef unsigned short u16;
typedef short short8 __attribute__((ext_vector_type(8)));
typedef float f32x4 __attribute__((ext_vector_type(4)));
typedef u16 u16x4 __attribute__((ext_vector_type(4)));
typedef const __attribute__((address_space(1))) unsigned int g_u32;
typedef __attribute__((address_space(3))) unsigned int l_u32;

#define T_TOK 4096
#define HID 2048
#define NHEAD 16
#define HD 128
#define NSLOTS 16384
#define BATCH 2
#define SEQ 2048
#define NQKV 6144

__device__ __forceinline__ float bf2f(u16 u) {
    union { unsigned int i; float f; } v; v.i = ((unsigned int)u) << 16; return v.f;
}
__device__ __forceinline__ u16 f2bf(float f) {
    union { float f; unsigned int i; } v; v.f = f;
    unsigned int u = v.i;
    return (u16)((u + 0x7FFFu + ((u >> 16) & 1u)) >> 16);
}
__device__ __forceinline__ void gld_lds16(const u16* gsrc, u16* ldst) {
    __builtin_amdgcn_global_load_lds((g_u32*)gsrc, (l_u32*)ldst, 16, 0, 0);
}

// ---------------------------------------------------------------------------
// fp32 -> bf16 elementwise convert, 4 elems/thread.
// ---------------------------------------------------------------------------
__global__ __launch_bounds__(256)
void f32_to_bf16(const float* __restrict__ src, u16* __restrict__ dst) {
    const long i = ((long)blockIdx.x * 256 + threadIdx.x) * 4;
    const f32x4 v = *(const f32x4*)&src[i];
    u16x4 o;
    o[0] = f2bf(v[0]); o[1] = f2bf(v[1]); o[2] = f2bf(v[2]); o[3] = f2bf(v[3]);
    *(u16x4*)&dst[i] = o;
}

// ---------------------------------------------------------------------------
// C[M,N] = A[M,K](lda,bf16) * B[N,K]^T(ldb,bf16) + bias[N](fp32).
// Output bf16 (OUTF32=false) or fp32 (OUTF32=true).
// 128x128 tile, BK=32, 256 threads (4 waves, 2x2 of 64x64), MFMA 16x16x32.
// ---------------------------------------------------------------------------
template <bool OUTF32>
__global__ __launch_bounds__(256)
void gemm_bt_bias(const u16* __restrict__ A, int lda,
                  const u16* __restrict__ B, int ldb,
                  const float* __restrict__ bias, void* __restrict__ Cv, int ldc,
                  int M, int N, int K) {
    __shared__ __align__(16) u16 As[128 * 32];
    __shared__ __align__(16) u16 Bs[128 * 32];
    const int tid  = threadIdx.x;
    const int lane = tid & 63;
    const int wave = tid >> 6;
    const int quad = lane >> 4;
    const int l16  = lane & 15;
    const int wm   = wave & 1, wn = wave >> 1;
    const int m0 = blockIdx.y * 128;
    const int n0 = blockIdx.x * 128;

    f32x4 acc[4][4];
#pragma unroll
    for (int i = 0; i < 4; i++)
#pragma unroll
        for (int j = 0; j < 4; j++) acc[i][j] = (f32x4){0.f, 0.f, 0.f, 0.f};

    const int c0 = tid, c1 = tid + 256;   // 16B chunks: row=c>>2, col=(c&3)*8
    const long aoff0 = (long)(m0 + (c0 >> 2)) * lda + ((c0 & 3) * 8);
    const long aoff1 = (long)(m0 + (c1 >> 2)) * lda + ((c1 & 3) * 8);
    const long boff0 = (long)(n0 + (c0 >> 2)) * ldb + ((c0 & 3) * 8);
    const long boff1 = (long)(n0 + (c1 >> 2)) * ldb + ((c1 & 3) * 8);

    for (int k0 = 0; k0 < K; k0 += 32) {
        gld_lds16(A + aoff0 + k0, &As[c0 * 8]);
        gld_lds16(A + aoff1 + k0, &As[c1 * 8]);
        gld_lds16(B + boff0 + k0, &Bs[c0 * 8]);
        gld_lds16(B + boff1 + k0, &Bs[c1 * 8]);
        __syncthreads();
        short8 af[4], bf[4];
#pragma unroll
        for (int mi = 0; mi < 4; mi++)
            af[mi] = *(const short8*)&As[(wm * 64 + mi * 16 + l16) * 32 + quad * 8];
#pragma unroll
        for (int ni = 0; ni < 4; ni++)
            bf[ni] = *(const short8*)&Bs[(wn * 64 + ni * 16 + l16) * 32 + quad * 8];
#pragma unroll
        for (int mi = 0; mi < 4; mi++)
#pragma unroll
            for (int ni = 0; ni < 4; ni++)
                acc[mi][ni] = __builtin_amdgcn_mfma_f32_16x16x32_bf16(af[mi], bf[ni], acc[mi][ni], 0, 0, 0);
        __syncthreads();
    }

#pragma unroll
    for (int mi = 0; mi < 4; mi++)
#pragma unroll
        for (int ni = 0; ni < 4; ni++) {
            const int col = n0 + wn * 64 + ni * 16 + l16;
            const float bv = bias[col];
#pragma unroll
            for (int r = 0; r < 4; r++) {
                const int row = m0 + wm * 64 + mi * 16 + quad * 4 + r;
                const float val = acc[mi][ni][r] + bv;
                if (OUTF32) ((float*)Cv)[(long)row * ldc + col] = val;
                else        ((u16*)Cv)[(long)row * ldc + col]  = f2bf(val);
            }
        }
}

// ---------------------------------------------------------------------------
// NeoX RoPE on q,k in place in bf16 QKV buffer (cos/sin fp32) + stash v rows
// (bf16) so they survive flash overwriting the V region and the late
// v_cache memcpy. One thread per (token, head).
// ---------------------------------------------------------------------------
__global__ __launch_bounds__(256)
void rope_stash_kernel(u16* __restrict__ qkv, const float* __restrict__ cosb,
                       const float* __restrict__ sinb, u16* __restrict__ vstash) {
    const int g = blockIdx.x * 256 + threadIdx.x;   // t*NHEAD + h
    const int t = g >> 4, h = g & 15;
    u16* q = qkv + (size_t)t * NQKV + h * HD;
    u16* k = q + HID;
    u16* v = q + 2 * HID;
    u16* vs = vstash + (size_t)t * HID + h * HD;

    float c[16], s[16];
#pragma unroll
    for (int i = 0; i < 16; i++) { c[i] = cosb[t * 16 + i]; s[i] = sinb[t * 16 + i]; }
    {
        float x1[16], x2[16];
#pragma unroll
        for (int i = 0; i < 16; i++) { x1[i] = bf2f(q[i]); x2[i] = bf2f(q[i + 16]); }
#pragma unroll
        for (int i = 0; i < 16; i++) {
            q[i]      = f2bf(x1[i] * c[i] - x2[i] * s[i]);
            q[i + 16] = f2bf(x2[i] * c[i] + x1[i] * s[i]);
        }
    }
    {
        float x1[16], x2[16];
#pragma unroll
        for (int i = 0; i < 16; i++) { x1[i] = bf2f(k[i]); x2[i] = bf2f(k[i + 16]); }
#pragma unroll
        for (int i = 0; i < 16; i++) {
            k[i]      = f2bf(x1[i] * c[i] - x2[i] * s[i]);
            k[i + 16] = f2bf(x2[i] * c[i] + x1[i] * s[i]);
        }
    }
#pragma unroll
    for (int i = 0; i < 128; i += 4) *(u16x4*)&vs[i] = *(const u16x4*)&v[i];
}

// ---------------------------------------------------------------------------
// Transpose V (from QKV buffer, per head [S][HD]) into Vt [B*NH][HD][S], bf16.
// ---------------------------------------------------------------------------
__global__ __launch_bounds__(256)
void v_transpose(const u16* __restrict__ qkv, u16* __restrict__ vt) {
    __shared__ u16 lds[32][33];
    const int s0 = blockIdx.x * 32;
    const int d0 = blockIdx.y * 32;
    const int bh = blockIdx.z;
    const int b = bh >> 4, h = bh & 15;
    const int t = threadIdx.x;
    const int r = t >> 3;
    const int cc = (t & 7) * 4;
    const u16* src = qkv + (long)(b * SEQ + s0 + r) * NQKV + 2 * HID + h * HD + d0 + cc;
    u16x4 val = *(const u16x4*)src;
    lds[r][cc + 0] = val[0]; lds[r][cc + 1] = val[1];
    lds[r][cc + 2] = val[2]; lds[r][cc + 3] = val[3];
    __syncthreads();
    u16x4 o;
    o[0] = lds[cc + 0][r]; o[1] = lds[cc + 1][r];
    o[2] = lds[cc + 2][r]; o[3] = lds[cc + 3][r];
    u16* dst = vt + (long)bh * HD * SEQ + (long)(d0 + r) * SEQ + s0 + cc;
    *(u16x4*)dst = o;
}

// ---------------------------------------------------------------------------
// Causal flash attention (all bf16). Block: 64 Q-rows of one (b,h); 4 waves
// each own a 16-row Q-subtile. K staged from qkv K-region; V from Vt [HD][S].
// Output written into the (dead) V region of qkv.
// ---------------------------------------------------------------------------
__global__ __launch_bounds__(256)
void flash_attn(u16* __restrict__ qkv, const u16* __restrict__ vt) {
    __shared__ __align__(16) u16 Ks[32 * 128];
    __shared__ __align__(16) u16 Vs[128 * 32];
    __shared__ __align__(16) u16 Ps[4][16 * 32];
    const int tid  = threadIdx.x;
    const int lane = tid & 63;
    const int wave = tid >> 6;
    const int quad = lane >> 4;
    const int l16  = lane & 15;
    const int q0 = blockIdx.x * 64;
    const int bh = blockIdx.y;
    const int b = bh >> 4, h = bh & 15;
    const int qt = q0 + wave * 16;

    const u16* Qbase = qkv + (long)(b * SEQ) * NQKV + h * HD;
    const u16* Kbase = Qbase + HID;
    const u16* Vtb   = vt + (long)bh * HD * SEQ;

    short8 aq[4];
#pragma unroll
    for (int dk = 0; dk < 4; dk++)
        aq[dk] = *(const short8*)&Qbase[(long)(qt + l16) * NQKV + dk * 32 + quad * 8];

    f32x4 oacc[8];
#pragma unroll
    for (int i = 0; i < 8; i++) oacc[i] = (f32x4){0.f, 0.f, 0.f, 0.f};
    float m_old[4], l_run[4];
#pragma unroll
    for (int r = 0; r < 4; r++) { m_old[r] = -1e30f; l_run[r] = 0.f; }

    const int ntiles = q0 / 32 + 2;
    const float scale = 0.08838834764831845f;

    for (int kt = 0; kt < ntiles; kt++) {
        const int k0 = kt * 32;
        {   // stage K tile [32][128] and Vt tile [128][32]
            int c = tid;
            gld_lds16(&Kbase[(long)(k0 + (c >> 4)) * NQKV + (c & 15) * 8], &Ks[c * 8]);
            gld_lds16(&Vtb[(long)(c >> 2) * SEQ + k0 + (c & 3) * 8], &Vs[c * 8]);
            c = tid + 256;
            gld_lds16(&Kbase[(long)(k0 + (c >> 4)) * NQKV + (c & 15) * 8], &Ks[c * 8]);
            gld_lds16(&Vtb[(long)(c >> 2) * SEQ + k0 + (c & 3) * 8], &Vs[c * 8]);
        }
        __syncthreads();

        f32x4 sacc[2];
        sacc[0] = (f32x4){0.f, 0.f, 0.f, 0.f};
        sacc[1] = (f32x4){0.f, 0.f, 0.f, 0.f};
#pragma unroll
        for (int dk = 0; dk < 4; dk++) {
            short8 bk0 = *(const short8*)&Ks[(l16) * 128 + dk * 32 + quad * 8];
            short8 bk1 = *(const short8*)&Ks[(16 + l16) * 128 + dk * 32 + quad * 8];
            sacc[0] = __builtin_amdgcn_mfma_f32_16x16x32_bf16(aq[dk], bk0, sacc[0], 0, 0, 0);
            sacc[1] = __builtin_amdgcn_mfma_f32_16x16x32_bf16(aq[dk], bk1, sacc[1], 0, 0, 0);
        }

        float sv[2][4];
#pragma unroll
        for (int st = 0; st < 2; st++)
#pragma unroll
            for (int r = 0; r < 4; r++) {
                float x = sacc[st][r] * scale;
                const int kg = k0 + st * 16 + l16;
                const int qg = qt + quad * 4 + r;
                if (kg > qg) x = -1e30f;
                sv[st][r] = x;
            }

        float alpha[4];
#pragma unroll
        for (int r = 0; r < 4; r++) {
            float mv = fmaxf(sv[0][r], sv[1][r]);
#pragma unroll
            for (int sh = 1; sh < 16; sh <<= 1) mv = fmaxf(mv, __shfl_xor(mv, sh));
            const float mnew = fmaxf(m_old[r], mv);
            alpha[r] = __expf(m_old[r] - mnew);
            const float p0 = __expf(sv[0][r] - mnew);
            const float p1 = __expf(sv[1][r] - mnew);
            sv[0][r] = p0; sv[1][r] = p1;
            float ls = p0 + p1;
#pragma unroll
            for (int sh = 1; sh < 16; sh <<= 1) ls += __shfl_xor(ls, sh);
            l_run[r] = l_run[r] * alpha[r] + ls;
            m_old[r] = mnew;
        }

#pragma unroll
        for (int dt = 0; dt < 8; dt++)
#pragma unroll
            for (int r = 0; r < 4; r++) oacc[dt][r] *= alpha[r];

        // P: C-layout -> LDS -> A-layout (bf16)
#pragma unroll
        for (int st = 0; st < 2; st++)
#pragma unroll
            for (int r = 0; r < 4; r++)
                Ps[wave][(quad * 4 + r) * 32 + st * 16 + l16] = f2bf(sv[st][r]);
        __syncthreads();
        const short8 ap = *(const short8*)&Ps[wave][l16 * 32 + quad * 8];
#pragma unroll
        for (int dt = 0; dt < 8; dt++) {
            short8 bv = *(const short8*)&Vs[(dt * 16 + l16) * 32 + quad * 8];
            oacc[dt] = __builtin_amdgcn_mfma_f32_16x16x32_bf16(ap, bv, oacc[dt], 0, 0, 0);
        }
        __syncthreads();
    }

    // write attn output into the dead V region of qkv
    u16* outp = qkv + (long)(b * SEQ + qt) * NQKV + 2 * HID + h * HD;
#pragma unroll
    for (int r = 0; r < 4; r++) {
        const float inv = 1.0f / fmaxf(l_run[r], 1e-30f);
#pragma unroll
        for (int dt = 0; dt < 8; dt++) {
            const int row = quad * 4 + r;
            const int col = dt * 16 + l16;
            outp[(long)row * NQKV + col] = f2bf(oacc[dt][r] * inv);
        }
    }
}

// ---------------------------------------------------------------------------
// Scatter roped k rows (bf16 in qkv K region) into fp32 out_k at slot rows.
// ---------------------------------------------------------------------------
__global__ __launch_bounds__(256)
void scatter_k(const u16* __restrict__ qkv, const int* __restrict__ slots,
               float* __restrict__ outk) {
    const int g = blockIdx.x * 256 + threadIdx.x;
    const int t = g >> 4, h = g & 15;
    const u16* k = qkv + (size_t)t * NQKV + HID + h * HD;
    float* dst = outk + (size_t)slots[t] * HID + h * HD;
#pragma unroll
    for (int i = 0; i < 128; i += 4) {
        const u16x4 a = *(const u16x4*)&k[i];
        f32x4 f; f[0] = bf2f(a[0]); f[1] = bf2f(a[1]); f[2] = bf2f(a[2]); f[3] = bf2f(a[3]);
        *(f32x4*)&dst[i] = f;
    }
}

// ---------------------------------------------------------------------------
// Scatter stashed v rows (bf16) into fp32 out_v at slot rows.
// ---------------------------------------------------------------------------
__global__ __launch_bounds__(256)
void scatter_v(const u16* __restrict__ vstash, const int* __restrict__ slots,
               float* __restrict__ outv) {
    const int g = blockIdx.x * 256 + threadIdx.x;
    const int t = g >> 4, h = g & 15;
    const u16* v = vstash + (size_t)t * HID + h * HD;
    float* dst = outv + (size_t)slots[t] * HID + h * HD;
#pragma unroll
    for (int i = 0; i < 128; i += 4) {
        const u16x4 a = *(const u16x4*)&v[i];
        f32x4 f; f[0] = bf2f(a[0]); f[1] = bf2f(a[1]); f[2] = bf2f(a[2]); f[3] = bf2f(a[3]);
        *(f32x4*)&dst[i] = f;
    }
}

// ---------------------------------------------------------------------------
extern "C" void kernel_launch(void* const* d_in, const int* in_sizes, int n_in,
                              void* d_out, int out_size, void* d_ws, size_t ws_size,
                              hipStream_t stream) {
    (void)in_sizes; (void)n_in; (void)out_size; (void)ws_size;
    const float* hidden  = (const float*)d_in[0];
    const float* cosb    = (const float*)d_in[1];
    const float* sinb    = (const float*)d_in[2];
    const float* w_qkv   = (const float*)d_in[3];
    const float* b_qkv   = (const float*)d_in[4];
    const float* w_dense = (const float*)d_in[5];
    const float* b_dense = (const float*)d_in[6];
    const float* k_cache = (const float*)d_in[7];
    const float* v_cache = (const float*)d_in[8];
    const int*   slots   = (const int*)d_in[9];

    float* out0 = (float*)d_out;                       // [4096][2048] fp32 (final)
    float* outk = out0 + (size_t)T_TOK * HID;          // [16384][16][128] fp32 (final)
    float* outv = outk + (size_t)NSLOTS * NHEAD * HD;  // [16384][16][128] fp32 (final)

    // Scratch inside d_out's cache regions (dead until the late cache build):
    //   outk region (128 MiB): hidden_bf(16) | wqkv_bf(24) | vt(16) | wd_bf(8)
    //   outv region (128 MiB): qkv_bf(48)  [V slice becomes attn output]
    u16* hidden_bf = (u16*)outk;
    u16* wqkv_bf   = hidden_bf + (size_t)T_TOK * HID;          // +8.4M u16
    u16* vt        = wqkv_bf + (size_t)NQKV * HID;             // +12.6M u16
    u16* wd_bf     = vt + (size_t)BATCH * NHEAD * HD * SEQ;    // +8.4M u16
    u16* qkv       = (u16*)outv;
    u16* vstash    = (u16*)d_ws;                               // 16 MiB

    // 1) converts
    f32_to_bf16<<<(T_TOK * HID) / 1024, 256, 0, stream>>>(hidden, hidden_bf);
    f32_to_bf16<<<(NQKV * HID) / 1024, 256, 0, stream>>>(w_qkv, wqkv_bf);
    f32_to_bf16<<<(HID * HID) / 1024, 256, 0, stream>>>(w_dense, wd_bf);

    // 2) QKV GEMM (bf16 out into outv region)
    dim3 g1(NQKV / 128, T_TOK / 128);
    gemm_bt_bias<false><<<g1, 256, 0, stream>>>(hidden_bf, HID, wqkv_bf, HID,
                                                b_qkv, qkv, NQKV, T_TOK, NQKV, HID);

    // 3) RoPE in place + v stash
    rope_stash_kernel<<<(T_TOK * NHEAD) / 256, 256, 0, stream>>>(qkv, cosb, sinb, vstash);

    // 4) V transpose for flash B-operand
    dim3 g2(SEQ / 32, HD / 32, BATCH * NHEAD);
    v_transpose<<<g2, 256, 0, stream>>>(qkv, vt);

    // 5) flash attention (attn -> qkv V region)
    dim3 g3(SEQ / 64, BATCH * NHEAD);
    flash_attn<<<g3, 256, 0, stream>>>(qkv, vt);

    // 6) dense GEMM -> fp32 final out
    dim3 g4(HID / 128, T_TOK / 128);
    gemm_bt_bias<true><<<g4, 256, 0, stream>>>(qkv + 2 * HID, NQKV, wd_bf, HID,
                                               b_dense, out0, HID, T_TOK, HID, HID);

    // 7) cache build: k first (reads qkv in outv region, writes outk region),
    //    then v (wipes outv with v_cache copy, scatter from vstash).
    const size_t cache_bytes = (size_t)NSLOTS * NHEAD * HD * sizeof(float);
    hipMemcpyAsync(outk, k_cache, cache_bytes, hipMemcpyDeviceToDevice, stream);
    scatter_k<<<(T_TOK * NHEAD) / 256, 256, 0, stream>>>(qkv, slots, outk);
    hipMemcpyAsync(outv, v_cache, cache_bytes, hipMemcpyDeviceToDevice, stream);
    scatter_v<<<(T_TOK * NHEAD) / 256, 256, 0, stream>>>(vstash, slots, outv);
}

// Round 4
// 949.071 us; speedup vs baseline: 1.1441x; 1.1441x over previous
//
#include <hip/hip_runtime.h>
#include <stdint.h>

typedef unsigned short u16;
typedef short short8 __attribute__((ext_vector_type(8)));
typedef float f32x4 __attribute__((ext_vector_type(4)));
typedef u16 u16x4 __attribute__((ext_vector_type(4)));
typedef const __attribute__((address_space(1))) unsigned int g_u32;
typedef __attribute__((address_space(3))) unsigned int l_u32;

#define T_TOK 4096
#define HID 2048
#define NHEAD 16
#define HD 128
#define NSLOTS 16384
#define BATCH 2
#define SEQ 2048
#define NQKV 6144

__device__ __forceinline__ float bf2f(u16 u) {
    union { unsigned int i; float f; } v; v.i = ((unsigned int)u) << 16; return v.f;
}
__device__ __forceinline__ u16 f2bf(float f) {
    union { float f; unsigned int i; } v; v.f = f;
    unsigned int u = v.i;
    return (u16)((u + 0x7FFFu + ((u >> 16) & 1u)) >> 16);
}
__device__ __forceinline__ void gld_lds16(const u16* gsrc, u16* ldst) {
    __builtin_amdgcn_global_load_lds((g_u32*)gsrc, (l_u32*)ldst, 16, 0, 0);
}

// ---------------------------------------------------------------------------
// fp32 -> bf16 elementwise convert, 4 elems/thread.
// ---------------------------------------------------------------------------
__global__ __launch_bounds__(256)
void f32_to_bf16(const float* __restrict__ src, u16* __restrict__ dst) {
    const long i = ((long)blockIdx.x * 256 + threadIdx.x) * 4;
    const f32x4 v = *(const f32x4*)&src[i];
    u16x4 o;
    o[0] = f2bf(v[0]); o[1] = f2bf(v[1]); o[2] = f2bf(v[2]); o[3] = f2bf(v[3]);
    *(u16x4*)&dst[i] = o;
}

// ---------------------------------------------------------------------------
// C[M,N] = A[M,K](lda,bf16) * B[N,K]^T(ldb,bf16) + bias[N](fp32).
// 128x128 tile, BK=32, 256 threads. LDS rows are 4x16B chunks; chunk c of
// row r stored at c^((r>>1)&3): turns the 8-way ds_read_b128 conflict into
// 2-way (free, m136). Staging permutes the source chunk per lane so
// global_load_lds's wave-uniform-base+lane*16 dest stays valid.
// ---------------------------------------------------------------------------
template <bool OUTF32>
__global__ __launch_bounds__(256)
void gemm_bt_bias(const u16* __restrict__ A, int lda,
                  const u16* __restrict__ B, int ldb,
                  const float* __restrict__ bias, void* __restrict__ Cv, int ldc,
                  int M, int N, int K) {
    __shared__ __align__(16) u16 As[128 * 32];
    __shared__ __align__(16) u16 Bs[128 * 32];
    const int tid  = threadIdx.x;
    const int lane = tid & 63;
    const int wave = tid >> 6;
    const int quad = lane >> 4;
    const int l16  = lane & 15;
    const int wm   = wave & 1, wn = wave >> 1;
    const int m0 = blockIdx.y * 128;
    const int n0 = blockIdx.x * 128;

    f32x4 acc[4][4];
#pragma unroll
    for (int i = 0; i < 4; i++)
#pragma unroll
        for (int j = 0; j < 4; j++) acc[i][j] = (f32x4){0.f, 0.f, 0.f, 0.f};

    // slot s: row r=s>>2, stored-chunk cp=s&3, source chunk c=cp^((r>>1)&3)
    const int s0 = tid, s1 = tid + 256;
    const int r0 = s0 >> 2, r1 = s1 >> 2;
    const int cs0 = (s0 & 3) ^ ((r0 >> 1) & 3);
    const int cs1 = (s1 & 3) ^ ((r1 >> 1) & 3);
    const long aoff0 = (long)(m0 + r0) * lda + cs0 * 8;
    const long aoff1 = (long)(m0 + r1) * lda + cs1 * 8;
    const long boff0 = (long)(n0 + r0) * ldb + cs0 * 8;
    const long boff1 = (long)(n0 + r1) * ldb + cs1 * 8;
    const int rcp = (quad ^ ((l16 >> 1) & 3)) * 8;   // read-side swizzled chunk

    for (int k0 = 0; k0 < K; k0 += 32) {
        gld_lds16(A + aoff0 + k0, &As[s0 * 8]);
        gld_lds16(A + aoff1 + k0, &As[s1 * 8]);
        gld_lds16(B + boff0 + k0, &Bs[s0 * 8]);
        gld_lds16(B + boff1 + k0, &Bs[s1 * 8]);
        __syncthreads();
        short8 af[4], bf[4];
#pragma unroll
        for (int mi = 0; mi < 4; mi++)
            af[mi] = *(const short8*)&As[(wm * 64 + mi * 16 + l16) * 32 + rcp];
#pragma unroll
        for (int ni = 0; ni < 4; ni++)
            bf[ni] = *(const short8*)&Bs[(wn * 64 + ni * 16 + l16) * 32 + rcp];
#pragma unroll
        for (int mi = 0; mi < 4; mi++)
#pragma unroll
            for (int ni = 0; ni < 4; ni++)
                acc[mi][ni] = __builtin_amdgcn_mfma_f32_16x16x32_bf16(af[mi], bf[ni], acc[mi][ni], 0, 0, 0);
        __syncthreads();
    }

#pragma unroll
    for (int mi = 0; mi < 4; mi++)
#pragma unroll
        for (int ni = 0; ni < 4; ni++) {
            const int col = n0 + wn * 64 + ni * 16 + l16;
            const float bv = bias[col];
#pragma unroll
            for (int r = 0; r < 4; r++) {
                const int row = m0 + wm * 64 + mi * 16 + quad * 4 + r;
                const float val = acc[mi][ni][r] + bv;
                if (OUTF32) ((float*)Cv)[(long)row * ldc + col] = val;
                else        ((u16*)Cv)[(long)row * ldc + col]  = f2bf(val);
            }
        }
}

// ---------------------------------------------------------------------------
// NeoX RoPE on q,k in place in bf16 QKV buffer + stash v rows (bf16).
// ---------------------------------------------------------------------------
__global__ __launch_bounds__(256)
void rope_stash_kernel(u16* __restrict__ qkv, const float* __restrict__ cosb,
                       const float* __restrict__ sinb, u16* __restrict__ vstash) {
    const int g = blockIdx.x * 256 + threadIdx.x;   // t*NHEAD + h
    const int t = g >> 4, h = g & 15;
    u16* q = qkv + (size_t)t * NQKV + h * HD;
    u16* k = q + HID;
    u16* v = q + 2 * HID;
    u16* vs = vstash + (size_t)t * HID + h * HD;

    float c[16], s[16];
#pragma unroll
    for (int i = 0; i < 16; i++) { c[i] = cosb[t * 16 + i]; s[i] = sinb[t * 16 + i]; }
    {
        float x1[16], x2[16];
#pragma unroll
        for (int i = 0; i < 16; i++) { x1[i] = bf2f(q[i]); x2[i] = bf2f(q[i + 16]); }
#pragma unroll
        for (int i = 0; i < 16; i++) {
            q[i]      = f2bf(x1[i] * c[i] - x2[i] * s[i]);
            q[i + 16] = f2bf(x2[i] * c[i] + x1[i] * s[i]);
        }
    }
    {
        float x1[16], x2[16];
#pragma unroll
        for (int i = 0; i < 16; i++) { x1[i] = bf2f(k[i]); x2[i] = bf2f(k[i + 16]); }
#pragma unroll
        for (int i = 0; i < 16; i++) {
            k[i]      = f2bf(x1[i] * c[i] - x2[i] * s[i]);
            k[i + 16] = f2bf(x2[i] * c[i] + x1[i] * s[i]);
        }
    }
#pragma unroll
    for (int i = 0; i < 128; i += 4) *(u16x4*)&vs[i] = *(const u16x4*)&v[i];
}

// ---------------------------------------------------------------------------
// Transpose V (from QKV buffer, per head [S][HD]) into Vt [B*NH][HD][S], bf16.
// ---------------------------------------------------------------------------
__global__ __launch_bounds__(256)
void v_transpose(const u16* __restrict__ qkv, u16* __restrict__ vt) {
    __shared__ u16 lds[32][33];
    const int s0 = blockIdx.x * 32;
    const int d0 = blockIdx.y * 32;
    const int bh = blockIdx.z;
    const int b = bh >> 4, h = bh & 15;
    const int t = threadIdx.x;
    const int r = t >> 3;
    const int cc = (t & 7) * 4;
    const u16* src = qkv + (long)(b * SEQ + s0 + r) * NQKV + 2 * HID + h * HD + d0 + cc;
    u16x4 val = *(const u16x4*)src;
    lds[r][cc + 0] = val[0]; lds[r][cc + 1] = val[1];
    lds[r][cc + 2] = val[2]; lds[r][cc + 3] = val[3];
    __syncthreads();
    u16x4 o;
    o[0] = lds[cc + 0][r]; o[1] = lds[cc + 1][r];
    o[2] = lds[cc + 2][r]; o[3] = lds[cc + 3][r];
    u16* dst = vt + (long)bh * HD * SEQ + (long)(d0 + r) * SEQ + s0 + cc;
    *(u16x4*)dst = o;
}

// ---------------------------------------------------------------------------
// Causal flash attention, K-tile=64, 2 barriers/iter, swizzled LDS.
// Block: 64 Q-rows of one (b,h); wave w owns Q rows [q0+16w, q0+16w+16).
// Chunk swizzle: 16B chunk c of LDS row r lives at slot c^(r&7) -> all
// MFMA-operand ds_read_b128 are 2-way (free). Heavy blocks dispatch first.
// Output written into the (dead) V region of qkv.
// ---------------------------------------------------------------------------
__global__ __launch_bounds__(256)
void flash_attn(u16* __restrict__ qkv, const u16* __restrict__ vt) {
    __shared__ __align__(16) u16 Ks[64 * 128];    // [k-row][d], 16 chunks/row
    __shared__ __align__(16) u16 Vs[128 * 64];    // [d-row][k], 8 chunks/row
    __shared__ __align__(16) u16 Ps[4][16 * 64];  // per-wave [q-row][k], 8 chunks/row
    const int tid  = threadIdx.x;
    const int lane = tid & 63;
    const int wave = tid >> 6;
    const int quad = lane >> 4;
    const int l16  = lane & 15;
    const int q0 = ((int)gridDim.x - 1 - (int)blockIdx.x) * 64;  // heavy first
    const int bh = blockIdx.y;
    const int b = bh >> 4, h = bh & 15;
    const int qt = q0 + wave * 16;

    const u16* Qbase = qkv + (long)(b * SEQ) * NQKV + h * HD;
    const u16* Kbase = Qbase + HID;
    const u16* Vtb   = vt + (long)bh * HD * SEQ;

    short8 aq[4];
#pragma unroll
    for (int dk = 0; dk < 4; dk++)
        aq[dk] = *(const short8*)&Qbase[(long)(qt + l16) * NQKV + dk * 32 + quad * 8];

    f32x4 oacc[8];
#pragma unroll
    for (int i = 0; i < 8; i++) oacc[i] = (f32x4){0.f, 0.f, 0.f, 0.f};
    float m_old[4], l_run[4];
#pragma unroll
    for (int r = 0; r < 4; r++) { m_old[r] = -1e30f; l_run[r] = 0.f; }

    // staging slot precompute (4 K-slots + 4 V-slots per thread)
    int ksr[4], ksc[4], vsr[4], vsc[4];
#pragma unroll
    for (int i = 0; i < 4; i++) {
        const int s = i * 256 + tid;
        ksr[i] = s >> 4; ksc[i] = (s & 15) ^ (ksr[i] & 7);
        vsr[i] = s >> 3; vsc[i] = (s & 7) ^ (vsr[i] & 7);
    }

    const int ntiles = q0 / 64 + 1;
    const float scale = 0.08838834764831845f;
    const int swz = (l16 & 7);    // read-side row-swizzle term

    for (int kt = 0; kt < ntiles; kt++) {
        const int k0 = kt * 64;
#pragma unroll
        for (int i = 0; i < 4; i++) {
            gld_lds16(&Kbase[(long)(k0 + ksr[i]) * NQKV + ksc[i] * 8], &Ks[(i * 256 + tid) * 8]);
            gld_lds16(&Vtb[(long)vsr[i] * SEQ + k0 + vsc[i] * 8], &Vs[(i * 256 + tid) * 8]);
        }
        __syncthreads();

        // S = Q K^T  (4 k-subtiles of 16)
        f32x4 sacc[4];
#pragma unroll
        for (int st = 0; st < 4; st++) sacc[st] = (f32x4){0.f, 0.f, 0.f, 0.f};
#pragma unroll
        for (int dk = 0; dk < 4; dk++) {
            const int cp = ((dk * 4 + quad) ^ swz) * 8;
#pragma unroll
            for (int st = 0; st < 4; st++) {
                const short8 bk = *(const short8*)&Ks[(st * 16 + l16) * 128 + cp];
                sacc[st] = __builtin_amdgcn_mfma_f32_16x16x32_bf16(aq[dk], bk, sacc[st], 0, 0, 0);
            }
        }

        float sv[4][4];
#pragma unroll
        for (int st = 0; st < 4; st++) {
            const int kg = k0 + st * 16 + l16;
#pragma unroll
            for (int r = 0; r < 4; r++) {
                float x = sacc[st][r] * scale;
                if (kg > qt + quad * 4 + r) x = -1e30f;
                sv[st][r] = x;
            }
        }

        float alpha[4];
#pragma unroll
        for (int r = 0; r < 4; r++) {
            float mv = fmaxf(fmaxf(sv[0][r], sv[1][r]), fmaxf(sv[2][r], sv[3][r]));
#pragma unroll
            for (int sh = 1; sh < 16; sh <<= 1) mv = fmaxf(mv, __shfl_xor(mv, sh));
            const float mnew = fmaxf(m_old[r], mv);
            alpha[r] = __expf(m_old[r] - mnew);
            float ls = 0.f;
#pragma unroll
            for (int st = 0; st < 4; st++) {
                const float p = __expf(sv[st][r] - mnew);
                sv[st][r] = p; ls += p;
            }
#pragma unroll
            for (int sh = 1; sh < 16; sh <<= 1) ls += __shfl_xor(ls, sh);
            l_run[r] = l_run[r] * alpha[r] + ls;
            m_old[r] = mnew;
        }

#pragma unroll
        for (int dt = 0; dt < 8; dt++)
#pragma unroll
            for (int r = 0; r < 4; r++) oacc[dt][r] *= alpha[r];

        // P: C-layout -> LDS (swizzled) -> A-layout. Wave-local: NO barrier.
#pragma unroll
        for (int st = 0; st < 4; st++) {
            const int cbase = st * 2 + (l16 >> 3);
#pragma unroll
            for (int r = 0; r < 4; r++) {
                const int row = quad * 4 + r;
                Ps[wave][row * 64 + (cbase ^ (row & 7)) * 8 + (l16 & 7)] = f2bf(sv[st][r]);
            }
        }
        short8 ap[2];
#pragma unroll
        for (int kk = 0; kk < 2; kk++)
            ap[kk] = *(const short8*)&Ps[wave][l16 * 64 + ((kk * 4 + quad) ^ swz) * 8];
#pragma unroll
        for (int dt = 0; dt < 8; dt++) {
#pragma unroll
            for (int kk = 0; kk < 2; kk++) {
                const short8 bv = *(const short8*)&Vs[(dt * 16 + l16) * 64 + ((kk * 4 + quad) ^ swz) * 8];
                oacc[dt] = __builtin_amdgcn_mfma_f32_16x16x32_bf16(ap[kk], bv, oacc[dt], 0, 0, 0);
            }
        }
        __syncthreads();
    }

    // write attn output into the dead V region of qkv
    u16* outp = qkv + (long)(b * SEQ + qt) * NQKV + 2 * HID + h * HD;
#pragma unroll
    for (int r = 0; r < 4; r++) {
        const float inv = 1.0f / fmaxf(l_run[r], 1e-30f);
#pragma unroll
        for (int dt = 0; dt < 8; dt++)
            outp[(long)(quad * 4 + r) * NQKV + dt * 16 + l16] = f2bf(oacc[dt][r] * inv);
    }
}

// ---------------------------------------------------------------------------
// Scatter roped k rows (bf16 in qkv K region) into fp32 out_k at slot rows.
// ---------------------------------------------------------------------------
__global__ __launch_bounds__(256)
void scatter_k(const u16* __restrict__ qkv, const int* __restrict__ slots,
               float* __restrict__ outk) {
    const int g = blockIdx.x * 256 + threadIdx.x;
    const int t = g >> 4, h = g & 15;
    const u16* k = qkv + (size_t)t * NQKV + HID + h * HD;
    float* dst = outk + (size_t)slots[t] * HID + h * HD;
#pragma unroll
    for (int i = 0; i < 128; i += 4) {
        const u16x4 a = *(const u16x4*)&k[i];
        f32x4 f; f[0] = bf2f(a[0]); f[1] = bf2f(a[1]); f[2] = bf2f(a[2]); f[3] = bf2f(a[3]);
        *(f32x4*)&dst[i] = f;
    }
}

// ---------------------------------------------------------------------------
// Scatter stashed v rows (bf16) into fp32 out_v at slot rows.
// ---------------------------------------------------------------------------
__global__ __launch_bounds__(256)
void scatter_v(const u16* __restrict__ vstash, const int* __restrict__ slots,
               float* __restrict__ outv) {
    const int g = blockIdx.x * 256 + threadIdx.x;
    const int t = g >> 4, h = g & 15;
    const u16* v = vstash + (size_t)t * HID + h * HD;
    float* dst = outv + (size_t)slots[t] * HID + h * HD;
#pragma unroll
    for (int i = 0; i < 128; i += 4) {
        const u16x4 a = *(const u16x4*)&v[i];
        f32x4 f; f[0] = bf2f(a[0]); f[1] = bf2f(a[1]); f[2] = bf2f(a[2]); f[3] = bf2f(a[3]);
        *(f32x4*)&dst[i] = f;
    }
}

// ---------------------------------------------------------------------------
extern "C" void kernel_launch(void* const* d_in, const int* in_sizes, int n_in,
                              void* d_out, int out_size, void* d_ws, size_t ws_size,
                              hipStream_t stream) {
    (void)in_sizes; (void)n_in; (void)out_size; (void)ws_size;
    const float* hidden  = (const float*)d_in[0];
    const float* cosb    = (const float*)d_in[1];
    const float* sinb    = (const float*)d_in[2];
    const float* w_qkv   = (const float*)d_in[3];
    const float* b_qkv   = (const float*)d_in[4];
    const float* w_dense = (const float*)d_in[5];
    const float* b_dense = (const float*)d_in[6];
    const float* k_cache = (const float*)d_in[7];
    const float* v_cache = (const float*)d_in[8];
    const int*   slots   = (const int*)d_in[9];

    float* out0 = (float*)d_out;                       // [4096][2048] fp32 (final)
    float* outk = out0 + (size_t)T_TOK * HID;          // [16384][16][128] fp32 (final)
    float* outv = outk + (size_t)NSLOTS * NHEAD * HD;  // [16384][16][128] fp32 (final)

    // Scratch inside d_out's cache regions (dead until the late cache build):
    //   outk region (128 MiB): hidden_bf(16) | wqkv_bf(24) | vt(16) | wd_bf(8)
    //   outv region (128 MiB): qkv_bf(48)  [V slice becomes attn output]
    u16* hidden_bf = (u16*)outk;
    u16* wqkv_bf   = hidden_bf + (size_t)T_TOK * HID;
    u16* vt        = wqkv_bf + (size_t)NQKV * HID;
    u16* wd_bf     = vt + (size_t)BATCH * NHEAD * HD * SEQ;
    u16* qkv       = (u16*)outv;
    u16* vstash    = (u16*)d_ws;                       // 16 MiB

    // 1) converts
    f32_to_bf16<<<(T_TOK * HID) / 1024, 256, 0, stream>>>(hidden, hidden_bf);
    f32_to_bf16<<<(NQKV * HID) / 1024, 256, 0, stream>>>(w_qkv, wqkv_bf);
    f32_to_bf16<<<(HID * HID) / 1024, 256, 0, stream>>>(w_dense, wd_bf);

    // 2) QKV GEMM (bf16 out into outv region)
    dim3 g1(NQKV / 128, T_TOK / 128);
    gemm_bt_bias<false><<<g1, 256, 0, stream>>>(hidden_bf, HID, wqkv_bf, HID,
                                                b_qkv, qkv, NQKV, T_TOK, NQKV, HID);

    // 3) RoPE in place + v stash
    rope_stash_kernel<<<(T_TOK * NHEAD) / 256, 256, 0, stream>>>(qkv, cosb, sinb, vstash);

    // 4) V transpose for flash B-operand
    dim3 g2(SEQ / 32, HD / 32, BATCH * NHEAD);
    v_transpose<<<g2, 256, 0, stream>>>(qkv, vt);

    // 5) flash attention (attn -> qkv V region)
    dim3 g3(SEQ / 64, BATCH * NHEAD);
    flash_attn<<<g3, 256, 0, stream>>>(qkv, vt);

    // 6) dense GEMM -> fp32 final out
    dim3 g4(HID / 128, T_TOK / 128);
    gemm_bt_bias<true><<<g4, 256, 0, stream>>>(qkv + 2 * HID, NQKV, wd_bf, HID,
                                               b_dense, out0, HID, T_TOK, HID, HID);

    // 7) cache build: k first (reads qkv in outv region, writes outk region),
    //    then v (wipes outv with v_cache copy, scatter from vstash).
    const size_t cache_bytes = (size_t)NSLOTS * NHEAD * HD * sizeof(float);
    hipMemcpyAsync(outk, k_cache, cache_bytes, hipMemcpyDeviceToDevice, stream);
    scatter_k<<<(T_TOK * NHEAD) / 256, 256, 0, stream>>>(qkv, slots, outk);
    hipMemcpyAsync(outv, v_cache, cache_bytes, hipMemcpyDeviceToDevice, stream);
    scatter_v<<<(T_TOK * NHEAD) / 256, 256, 0, stream>>>(vstash, slots, outv);
}